// Round 8
// baseline (1291.456 us; speedup 1.0000x reference)
//
#include <hip/hip_runtime.h>

// NT-Xent loss, B=4096, D=256, N=16384, T=0.5.
// loss = mean_i( -pos_i + log(sum_{j!=i} exp(2*dot(zn_i, zn_j)) + 1e-12) )
//
// R10: tilek compute structure FROZEN at R9 (128x128 upper-tri tiles, 4 waves 2x2
// of 64x64, BK=32, double-buffered 2x16KB LDS, 1-deep prefetch, counted vmcnt(4),
// 2 raw barriers/K-tile, 3-bit granule swizzle, collapsed addressing, 4 blocks/CU).
// Two additions:
//  (1) s_sleep phase-stagger: co-resident blocks get distinct ~256-cyc offsets so
//      their MFMA bursts anti-phase instead of colliding (util was pinned at
//      1-wave-burst/period = lockstep signature).
//  (2) tail fused into tilek: per-row-block counters; the 128th contributor to a
//      128-row stripe reduces it (log-sum), the 128th stripe triggers the final
//      deterministic combine. rowlogf dispatch eliminated (3 kernels -> 2).
//
// ws layout:
//   [0, 8MB)        : zb   — l2-normalized z * 1.6986436, bf16, [16384][256]
//   [8MB, 16MB)     : part — f32 [128][16384] (column-block partial sums)
//   [16MB, +16KB)   : pospart[4096]
//   [+16KB, +512B)  : logpart[128]
//   [then, 129 u32] : cnt[0..127] per-row-block contribution counters, cnt[128] stripes-done
//                     (all zeroed by norm4k block 0 every launch)

typedef __bf16 bf16;
typedef __bf16 bf16x4 __attribute__((ext_vector_type(4)));
typedef __bf16 bf16x8 __attribute__((ext_vector_type(8)));
typedef float  f32x4  __attribute__((ext_vector_type(4)));

#define NTOT 16384
#define DDIM 256
// sqrt(2*log2(e)) : dot of scaled vectors = 2*log2(e)*dot, so exp2(acc)=exp(2*dot)
#define KSCL 1.6986436f

__device__ __forceinline__ float dot4(float4 a, float4 b) {
    return a.x * b.x + a.y * b.y + a.z * b.z + a.w * b.w;
}

// ---------------- kernel 1: normalize rows -> bf16 (scaled), plus positive-pair sims ----------------
__global__ __launch_bounds__(256) void norm4k(const float* __restrict__ z1,
                                              const float* __restrict__ z2,
                                              const float* __restrict__ z3,
                                              const float* __restrict__ z4,
                                              bf16* __restrict__ zb,
                                              float* __restrict__ pospart,
                                              unsigned* __restrict__ cnt) {
    if (blockIdx.x == 0 && threadIdx.x < 129) cnt[threadIdx.x] = 0u; // arm counters
    const int wave = threadIdx.x >> 6;
    const int lane = threadIdx.x & 63;
    const int i    = blockIdx.x * 4 + wave; // 0..4095
    const float4* p1 = (const float4*)(z1 + (size_t)i * DDIM);
    const float4* p2 = (const float4*)(z2 + (size_t)i * DDIM);
    const float4* p3 = (const float4*)(z3 + (size_t)i * DDIM);
    const float4* p4 = (const float4*)(z4 + (size_t)i * DDIM);
    float4 a = p1[lane], b = p2[lane], c = p3[lane], d = p4[lane];
    float s11 = dot4(a, a), s22 = dot4(b, b), s33 = dot4(c, c), s44 = dot4(d, d);
    float s12 = dot4(a, b), s23 = dot4(b, c), s34 = dot4(c, d), s41 = dot4(d, a);
#pragma unroll
    for (int m = 32; m >= 1; m >>= 1) {
        s11 += __shfl_xor(s11, m, 64); s22 += __shfl_xor(s22, m, 64);
        s33 += __shfl_xor(s33, m, 64); s44 += __shfl_xor(s44, m, 64);
        s12 += __shfl_xor(s12, m, 64); s23 += __shfl_xor(s23, m, 64);
        s34 += __shfl_xor(s34, m, 64); s41 += __shfl_xor(s41, m, 64);
    }
    const float m1 = fmaxf(sqrtf(s11), 1e-12f), m2 = fmaxf(sqrtf(s22), 1e-12f);
    const float m3 = fmaxf(sqrtf(s33), 1e-12f), m4 = fmaxf(sqrtf(s44), 1e-12f);
    const float i1 = 1.0f / m1, i2 = 1.0f / m2, i3 = 1.0f / m3, i4 = 1.0f / m4;
    const float t1 = i1 * KSCL, t2 = i2 * KSCL, t3 = i3 * KSCL, t4 = i4 * KSCL;
    bf16x4 o;
    o.x = (bf16)(a.x * t1); o.y = (bf16)(a.y * t1); o.z = (bf16)(a.z * t1); o.w = (bf16)(a.w * t1);
    *(bf16x4*)(zb + (size_t)i * DDIM + lane * 4) = o;
    o.x = (bf16)(b.x * t2); o.y = (bf16)(b.y * t2); o.z = (bf16)(b.z * t2); o.w = (bf16)(b.w * t2);
    *(bf16x4*)(zb + (size_t)(i + 4096) * DDIM + lane * 4) = o;
    o.x = (bf16)(c.x * t3); o.y = (bf16)(c.y * t3); o.z = (bf16)(c.z * t3); o.w = (bf16)(c.w * t3);
    *(bf16x4*)(zb + (size_t)(i + 8192) * DDIM + lane * 4) = o;
    o.x = (bf16)(d.x * t4); o.y = (bf16)(d.y * t4); o.z = (bf16)(d.z * t4); o.w = (bf16)(d.w * t4);
    *(bf16x4*)(zb + (size_t)(i + 12288) * DDIM + lane * 4) = o;
    if (lane == 0)
        pospart[i] = 2.0f * (s12 * i1 * i2 + s23 * i2 * i3 + s34 * i3 * i4 + s41 * i4 * i1);
}

// ---------------- stripe reduce: rows [X*128, X*128+128) -> logpart[X]; last stripe finalizes ----------------
__device__ __forceinline__ void stripe_reduce(int X, const float* __restrict__ part,
                                              float* __restrict__ logpart,
                                              const float* __restrict__ pospart,
                                              unsigned* __restrict__ cnt,
                                              float* __restrict__ out,
                                              char* lds, int tid) {
    const int wv = tid >> 6, ln = tid & 63;
    const int r  = (X << 7) + (tid >> 1);   // 2 threads per row
    const int ch = (tid & 1) << 6;          // each sums 64 column-blocks
    float s = 0.f;
#pragma unroll 8
    for (int j = 0; j < 64; ++j) s += part[(size_t)(ch + j) * NTOT + r];
    s += __shfl_xor(s, 1, 64);
    float v = ((tid & 1) == 0) ? logf(s + 1e-12f) : 0.f;
#pragma unroll
    for (int m = 2; m <= 32; m <<= 1) v += __shfl_xor(v, m, 64);
    float* red = (float*)lds;               // alias: K-loop LDS is dead here
    unsigned* dn = (unsigned*)(lds + 16);
    if (ln == 0) red[wv] = v;
    __syncthreads();
    if (tid == 0) {
        logpart[X] = red[0] + red[1] + red[2] + red[3];
        __threadfence();                    // release logpart[X]
        dn[0] = atomicAdd(&cnt[128], 1u);
    }
    __syncthreads();
    if (dn[0] == 127u) {                    // this block completed the last stripe
        __threadfence();                    // acquire all logpart writes
        float sp = 0.f;
#pragma unroll
        for (int kk = tid; kk < 4096; kk += 256) sp += pospart[kk];
        float sl = (tid < 128) ? logpart[tid] : 0.f;
#pragma unroll
        for (int m = 32; m >= 1; m >>= 1) { sp += __shfl_xor(sp, m, 64); sl += __shfl_xor(sl, m, 64); }
        float* rp = (float*)(lds + 64);
        float* rl = (float*)(lds + 96);
        if (ln == 0) { rp[wv] = sp; rl[wv] = sl; }
        __syncthreads();
        if (tid == 0) {
            float P = rp[0] + rp[1] + rp[2] + rp[3];
            float L = rl[0] + rl[1] + rl[2] + rl[3];
            out[0] = (L - P) / 16384.0f;
        }
    }
}

// ---------------- kernel 2: fused Gram-matrix exp-rowsum + tail, upper triangle ----------------
__global__ __launch_bounds__(256, 4) void tilek(const bf16* __restrict__ zb,
                                                float* __restrict__ part,
                                                float* __restrict__ logpart,
                                                const float* __restrict__ pospart,
                                                unsigned* __restrict__ cnt,
                                                float* __restrict__ out) {
    // 2 buffers x 16KB (A:8KB + B:8KB). Reductions aliased into buf0 after K-loop.
    __shared__ __attribute__((aligned(16))) char lds[32768];
    __shared__ unsigned sfl[2];

    const int tid  = threadIdx.x;
    const int wave = tid >> 6;
    const int lane = tid & 63;
    const int quad = lane >> 4;
    const int l15  = lane & 15;
    const int wr   = wave >> 1;   // 0..1 row half (64 rows of 128)
    const int wc   = wave & 1;    // 0..1 col half (64 cols of 128)

    // phase-stagger: distinct ~256-cyc offsets for co-resident blocks under either
    // consecutive (bid&3) or strided (bid>>8) block->CU mapping. Pure delay.
    const int skey = (blockIdx.x ^ (blockIdx.x >> 8)) & 3;
    switch (skey) {
        case 1: __builtin_amdgcn_s_sleep(4);  break;
        case 2: __builtin_amdgcn_s_sleep(8);  break;
        case 3: __builtin_amdgcn_s_sleep(12); break;
        default: break;
    }

    // XCD-chunked swizzle (bijective: 8256 = 8*1032), then triangular decode:
    // k -> (R, C), R <= C over 128 row-blocks; f(R) = R*128 - R*(R-1)/2
    const int k = (blockIdx.x & 7) * 1032 + (blockIdx.x >> 3);
    int R = (int)((257.0 - sqrt(257.0 * 257.0 - 8.0 * (double)k)) * 0.5);
    if (R > 127) R = 127;
    while (R < 127 && ((R + 1) * 128 - ((R + 1) * R) / 2) <= k) ++R;
    while (R > 0 && (R * 128 - (R * (R - 1)) / 2) > k) --R;
    const int C = R + (k - (R * 128 - (R * (R - 1)) / 2));
    const int dRC = (R - C) << 7; // 0 on diag; <= -128 off-diag (mask vacuous there)

    // ---- staging addressing (collapsed): pair-packed 128B lines, slot = g ^ (line&7) ----
    const int L0 = tid >> 3;
    const int g0 = (tid & 7) ^ (L0 & 7);
    const int srcoff = (2 * L0 + (g0 >> 2)) * 512 + ((g0 & 3) << 4);
    const char* gA0 = (const char*)zb + (size_t)(R << 7) * 512 + srcoff;
    const char* gB0 = (const char*)zb + (size_t)(C << 7) * 512 + srcoff;
    const int dst0 = tid << 4;

    auto STAGE = [&](int t, int bb) { // t = K-tile (0..7) -> +t*64B per row; bb = buffer base
#pragma unroll
        for (int i = 0; i < 2; ++i)
            __builtin_amdgcn_global_load_lds(
                (const __attribute__((address_space(1))) unsigned int*)(gA0 + (i << 15) + (t << 6)),
                (__attribute__((address_space(3))) unsigned int*)(lds + bb + (i << 12) + dst0),
                16, 0, 0);
#pragma unroll
        for (int i = 0; i < 2; ++i)
            __builtin_amdgcn_global_load_lds(
                (const __attribute__((address_space(1))) unsigned int*)(gB0 + (i << 15) + (t << 6)),
                (__attribute__((address_space(3))) unsigned int*)(lds + bb + 8192 + (i << 12) + dst0),
                16, 0, 0);
    };

    // ---- ds_read addressing (collapsed): off(rt) = off0 + rt*1024 ----
    const int sw    = ((((l15 & 1) << 2) | quad) ^ (l15 >> 1)) << 4;
    const int offA0 = (wr << 12) + ((l15 >> 1) << 7) + sw;
    const int offB0 = 8192 + (wc << 12) + ((l15 >> 1) << 7) + sw;

    f32x4 zero = {0.f, 0.f, 0.f, 0.f};
    f32x4 acc[4][4];
#pragma unroll
    for (int a = 0; a < 4; ++a)
#pragma unroll
        for (int b = 0; b < 4; ++b) acc[a][b] = zero;

    // prologue: stage K-tile 0 into buffer 0 (4 loads/thread)
    STAGE(0, 0);

#pragma unroll
    for (int ko = 0; ko < 8; ++ko) {
        const int bb = (ko & 1) << 14;
        if (ko < 7) STAGE(ko + 1, (~ko & 1) << 14); // 1-deep prefetch into other buffer
        if (ko < 7) asm volatile("s_waitcnt vmcnt(4)" ::: "memory");
        else        asm volatile("s_waitcnt vmcnt(0)" ::: "memory");
        __builtin_amdgcn_s_barrier();      // b1: buf[ko&1] staged by all waves
        __builtin_amdgcn_sched_barrier(0);

        bf16x8 af[4], bfr[4];
#pragma unroll
        for (int rt = 0; rt < 4; ++rt)
            af[rt] = *(const bf16x8*)(lds + bb + offA0 + (rt << 10));
#pragma unroll
        for (int ct = 0; ct < 4; ++ct)
            bfr[ct] = *(const bf16x8*)(lds + bb + offB0 + (ct << 10));

        __builtin_amdgcn_s_setprio(1);
#pragma unroll
        for (int rt = 0; rt < 4; ++rt)
#pragma unroll
            for (int ct = 0; ct < 4; ++ct)
                acc[rt][ct] = __builtin_amdgcn_mfma_f32_16x16x32_bf16(
                    af[rt], bfr[ct], acc[rt][ct], 0, 0, 0);
        __builtin_amdgcn_s_setprio(0);
        __builtin_amdgcn_s_barrier();      // b2: all waves done reading buf[ko&1]
        __builtin_amdgcn_sched_barrier(0);
    }

    // epilogue: e = exp2(acc) = exp(2*dot); mask r==c on diag tiles (vacuous off-diag).
    float* rsum = (float*)lds;            // [2][128]
    float* csum = (float*)(lds + 1024);   // [2][128]
    float cs[4] = {0.f, 0.f, 0.f, 0.f};
#pragma unroll
    for (int rt = 0; rt < 4; ++rt) {
        float rs[4] = {0.f, 0.f, 0.f, 0.f};
        const int rloc = (wr << 6) + (rt << 4) + (quad << 2);
#pragma unroll
        for (int ct = 0; ct < 4; ++ct) {
            const int cloc = (wc << 6) + (ct << 4) + l15;
#pragma unroll
            for (int rr = 0; rr < 4; ++rr) {
                float e;
                asm("v_exp_f32 %0, %1" : "=v"(e) : "v"(acc[rt][ct][rr]));
                if (rloc + rr + dRC == cloc) e = 0.f; // self-sim (diag tiles only)
                rs[rr] += e;
                cs[ct] += e;
            }
        }
#pragma unroll
        for (int m = 1; m <= 8; m <<= 1)
#pragma unroll
            for (int rr = 0; rr < 4; ++rr) rs[rr] += __shfl_xor(rs[rr], m, 64);
        if (l15 == 0) {
#pragma unroll
            for (int rr = 0; rr < 4; ++rr) rsum[(wc << 7) + rloc + rr] = rs[rr];
        }
    }
#pragma unroll
    for (int m = 16; m <= 32; m <<= 1)
#pragma unroll
        for (int ct = 0; ct < 4; ++ct) cs[ct] += __shfl_xor(cs[ct], m, 64);
    if (quad == 0) {
#pragma unroll
        for (int ct = 0; ct < 4; ++ct) csum[(wr << 7) + (wc << 6) + (ct << 4) + l15] = cs[ct];
    }
    __syncthreads();
    // column-major part [cblk][row]: rowsums -> cblk C, rows Rbase+tid;
    // colsums -> cblk R, rows Cbase+c. Exactly-once coverage (R2-proven).
    if (tid < 128) {
        part[(size_t)C * NTOT + (R << 7) + tid] = rsum[tid] + rsum[128 + tid];
    } else if (R != C) {
        const int c = tid - 128;
        part[(size_t)R * NTOT + (C << 7) + c] = csum[c] + csum[128 + c];
    }

    // ---- fused tail: count contributions; 128th contributor reduces the stripe ----
    // Row-block X needs 128 part-slot writes: tiles (X, cb>=X) rowsums + (cb<X, X) colsums.
    // This tile contributes to row-block R (rowsums) and, if off-diag, row-block C (colsums).
    __threadfence();      // release our part writes (device scope, per storing thread)
    __syncthreads();
    if (tid == 0) {
        unsigned a = atomicAdd(&cnt[R], 1u);
        unsigned b = (R != C) ? atomicAdd(&cnt[C], 1u) : 0u;
        sfl[0] = (a == 127u) ? 1u : 0u;
        sfl[1] = (R != C && b == 127u) ? 1u : 0u;
    }
    __syncthreads();
    if (sfl[0]) {
        __threadfence(); // acquire other contributors' part writes
        stripe_reduce(R, part, logpart, pospart, cnt, out, lds, tid);
    }
    if (sfl[1]) {
        __threadfence();
        __syncthreads();
        stripe_reduce(C, part, logpart, pospart, cnt, out, lds, tid);
    }
}

extern "C" void kernel_launch(void* const* d_in, const int* in_sizes, int n_in,
                              void* d_out, int out_size, void* d_ws, size_t ws_size,
                              hipStream_t stream) {
    const float* z1 = (const float*)d_in[0];
    const float* z2 = (const float*)d_in[1];
    const float* z3 = (const float*)d_in[2];
    const float* z4 = (const float*)d_in[3];
    float* out = (float*)d_out;

    const size_t PART_OFF = (size_t)(8u << 20);   // 8 MB: part [128][16384] f32
    const size_t POS_OFF  = (size_t)(16u << 20);  // 16 KB
    const size_t LOG_OFF  = POS_OFF + 16384;      // 512 B (128 floats)
    const size_t CNT_OFF  = LOG_OFF + 512;        // 129 u32

    char* ws = (char*)d_ws;
    bf16*  zb      = (bf16*)ws;
    float* part    = (float*)(ws + PART_OFF);
    float* pospart = (float*)(ws + POS_OFF);
    float* logpart = (float*)(ws + LOG_OFF);
    unsigned* cnt  = (unsigned*)(ws + CNT_OFF);

    norm4k<<<1024, 256, 0, stream>>>(z1, z2, z3, z4, zb, pospart, cnt);
    tilek<<<8256, 256, 0, stream>>>(zb, part, logpart, pospart, cnt, out);
}